// Round 5
// baseline (173.518 us; speedup 1.0000x reference)
//
#include <hip/hip_runtime.h>
#include <hip/hip_bf16.h>

typedef __attribute__((ext_vector_type(4))) float f32x4;

#define MAXS 4096  // max supported S for the LDS cumsum (here S=512)

// Kernel A: one block per batch row (grid-strided). Wave-shuffle inclusive scan
// of durations into LDS cumsum, then COALESCED frame->token map build: each
// thread binary-searches the LDS cumsum for its frames.
// map[b*T+t] = flat token id, or -1 for tail frames (t >= total).
__global__ __launch_bounds__(512)
void lr_buildmap_kernel(const int* __restrict__ dur, int* __restrict__ map,
                        const int* __restrict__ T_ptr, int BS, int BT) {
    const int T = *T_ptr;
    const int B = BT / T;
    const int S = BS / B;
    __shared__ int scum[MAXS];
    __shared__ int wtot[9];            // per-wave chunk totals (<=8 waves)
    const int tid  = threadIdx.x;
    const int lane = tid & 63;
    const int wv   = tid >> 6;
    const int nw   = blockDim.x >> 6;

    for (int row = blockIdx.x; row < B; row += gridDim.x) {
        int carry = 0;
        for (int base = 0; base < S; base += blockDim.x) {
            const int j = base + tid;
            __syncthreads();           // protect scum/wtot reuse
            int v = (j < S) ? dur[row * S + j] : 0;
            // wave-inclusive scan (64 lanes)
            int sum = v;
            #pragma unroll
            for (int off = 1; off < 64; off <<= 1) {
                int n = __shfl_up(sum, off, 64);
                if (lane >= off) sum += n;
            }
            if (lane == 63) wtot[wv] = sum;
            __syncthreads();
            if (tid == 0) {            // serial exclusive scan of <=8 wave totals
                int acc = 0;
                for (int w = 0; w < nw; ++w) { int t0 = wtot[w]; wtot[w] = acc; acc += t0; }
            }
            __syncthreads();
            const int chunk_off = wtot[wv];
            if (j < S) scum[j] = sum + chunk_off + carry;
            __syncthreads();
            // chunk total = last element written this chunk (inclusive)
            carry = scum[min(base + (int)blockDim.x, S) - 1];
        }
        __syncthreads();
        // coalesced map build: searchsorted(scum, t, side='right')
        for (int t = tid; t < T; t += blockDim.x) {
            int lo = 0, hi = S;
            while (lo < hi) {
                int mid = (lo + hi) >> 1;
                if (scum[mid] <= t) lo = mid + 1; else hi = mid;
            }
            map[row * T + t] = (lo < S) ? (row * S + lo) : -1;
        }
    }
}

// Kernel B: one thread per output float4. frame = g >> shift (no divisions).
// map load is wave-uniform (broadcast); x loads are coalesced & L2/L3-resident
// (x = 16.8 MB); out stores are nontemporal streaming (don't evict x from L2).
__global__ __launch_bounds__(256)
void lr_expand_kernel(const f32x4* __restrict__ x, const int* __restrict__ map,
                      f32x4* __restrict__ out, int n4, int shift) {
    const int g = blockIdx.x * blockDim.x + threadIdx.x;
    if (g >= n4) return;
    const int frame = g >> shift;
    const int lane  = g & ((1 << shift) - 1);
    const int tok   = map[frame];
    f32x4 v = (f32x4)(0.f, 0.f, 0.f, 0.f);
    if (tok >= 0) v = x[((size_t)tok << shift) + lane];
    __builtin_nontemporal_store(v, &out[g]);
}

extern "C" void kernel_launch(void* const* d_in, const int* in_sizes, int n_in,
                              void* d_out, int out_size, void* d_ws, size_t ws_size,
                              hipStream_t stream) {
    const float* x     = (const float*)d_in[0];
    const int*   dur   = (const int*)d_in[1];
    const int*   T_ptr = (const int*)d_in[2];

    const int BSH = in_sizes[0];     // B*S*H
    const int BS  = in_sizes[1];     // B*S
    const int H   = BSH / BS;        // 512
    const int BT  = out_size / H;    // B*T
    const int H4  = H / 4;           // 128 float4 per frame (power of 2)
    const int shift = __builtin_ctz(H4);

    int* map = (int*)d_ws;           // BT ints = 256 KB scratch

    lr_buildmap_kernel<<<64, 512, 0, stream>>>(dur, map, T_ptr, BS, BT);

    const int n4 = out_size / 4;     // BT * H4
    const int grid = (n4 + 255) / 256;
    lr_expand_kernel<<<grid, 256, 0, stream>>>((const f32x4*)x, map, (f32x4*)d_out,
                                               n4, shift);
}